// Round 1
// baseline (1530.958 us; speedup 1.0000x reference)
//
#include <hip/hip_runtime.h>
#include <math.h>

#define NN 50000
#define NE 800000
#define D  128

// ---------------- degree histogram (in-degree by dst) ----------------
__global__ __launch_bounds__(256) void k_deg(const int* __restrict__ ei,
                                             int* __restrict__ degi) {
    int e = blockIdx.x * 256 + threadIdx.x;   // grid sized exactly NE/256
    int dst = ei[NE + e];
    if ((unsigned)dst < NN) atomicAdd(&degi[dst], 1);
}

// ---------------- dinv = rsqrt(deg) with self-loop (+1) ----------------
__global__ __launch_bounds__(256) void k_dinv(const int* __restrict__ degi,
                                              float* __restrict__ dinv) {
    int i = blockIdx.x * 256 + threadIdx.x;
    if (i < NN) dinv[i] = rsqrtf((float)degi[i] + 1.0f);
}

// ---------------- edge scatter: aggh[dst] += h[src] * dinv[src]*dinv[dst] ----
// 32 threads per edge, float4 per thread (128 dims).
__global__ __launch_bounds__(256) void k_scatter(const int* __restrict__ ei,
                                                 const float* __restrict__ h,
                                                 const float* __restrict__ dinv,
                                                 float* __restrict__ aggh) {
    int t = blockIdx.x * 256 + threadIdx.x;
    int e = t >> 5;             // 8 edges per block; grid sized exactly
    int c = (t & 31) << 2;      // dim offset 0..124
    int src = ei[e];
    int dst = ei[NE + e];
    if ((unsigned)src >= NN || (unsigned)dst >= NN) return;  // safety
    float norm = dinv[src] * dinv[dst];
    const float4 hv = *(const float4*)(h + (size_t)src * D + c);
    float* ap = aggh + (size_t)dst * D + c;
    atomicAdd(ap + 0, hv.x * norm);
    atomicAdd(ap + 1, hv.y * norm);
    atomicAdd(ap + 2, hv.z * norm);
    atomicAdd(ap + 3, hv.w * norm);
}

// ---------------- fused: x = aggh + dinv^2*h ; y = xW + b ; LN ; tanh -------
// Block = 256 threads (4 waves). Block handles 16 rows: wave w -> rows base+4w..+3.
// Lane j accumulates columns j and j+64 for 4 rows (register blocking reuses
// each W element 4x -> LDS BW ~16KB/row instead of 64KB/row).
__global__ __launch_bounds__(256) void k_gemm_ln_tanh(
        const float* __restrict__ aggh, const float* __restrict__ h,
        const float* __restrict__ dinv, const float* __restrict__ Wg,
        const float* __restrict__ b,    const float* __restrict__ gamma,
        const float* __restrict__ beta, float* __restrict__ out) {
    __shared__ float Wl[D * D];       // 64 KB
    __shared__ float xs[4][4][D];     // 8 KB (per-wave private slices)
    int tid = threadIdx.x;

    // cooperative W load, float4-coalesced
#pragma unroll
    for (int i = 0; i < 16; i++) {
        int idx = i * 256 + tid;
        ((float4*)Wl)[idx] = ((const float4*)Wg)[idx];
    }

    int w = tid >> 6, lane = tid & 63;
    int rowBase = blockIdx.x * 16 + w * 4;    // grid = 3125 -> exactly 50000 rows

    // stage the 4 input rows for this wave (self-loop folded in here)
#pragma unroll
    for (int r = 0; r < 4; r++) {
        int row = rowBase + r;
        float d2 = dinv[row]; d2 *= d2;
        size_t off = (size_t)row * D;
        xs[w][r][lane]      = aggh[off + lane]      + d2 * h[off + lane];
        xs[w][r][lane + 64] = aggh[off + lane + 64] + d2 * h[off + lane + 64];
    }
    __syncthreads();   // covers W load + xs staging (uniform across block)

    float b0  = b[lane],     b1  = b[lane + 64];
    float g0  = gamma[lane], g1  = gamma[lane + 64];
    float be0 = beta[lane],  be1 = beta[lane + 64];

    float acc[4][2] = {{0,0},{0,0},{0,0},{0,0}};
#pragma unroll 8
    for (int k = 0; k < D; k++) {
        float w0 = Wl[k * D + lane];        // conflict-free (2-way is free)
        float w1 = Wl[k * D + lane + 64];
#pragma unroll
        for (int r = 0; r < 4; r++) {
            float xv = xs[w][r][k];         // same-address broadcast
            acc[r][0] = fmaf(xv, w0, acc[r][0]);
            acc[r][1] = fmaf(xv, w1, acc[r][1]);
        }
    }

#pragma unroll
    for (int r = 0; r < 4; r++) {
        float y0 = acc[r][0] + b0;
        float y1 = acc[r][1] + b1;
        // mean over 128 (2 per lane x 64 lanes), butterfly reduce
        float s = y0 + y1;
#pragma unroll
        for (int off = 32; off > 0; off >>= 1) s += __shfl_xor(s, off, 64);
        float m = s * (1.0f / 128.0f);
        float v0 = y0 - m, v1 = y1 - m;
        float vs = v0 * v0 + v1 * v1;
#pragma unroll
        for (int off = 32; off > 0; off >>= 1) vs += __shfl_xor(vs, off, 64);
        float rstd = rsqrtf(vs * (1.0f / 128.0f) + 1e-5f);
        int row = rowBase + r;
        out[(size_t)row * D + lane]      = tanhf(v0 * rstd * g0 + be0);
        out[(size_t)row * D + lane + 64] = tanhf(v1 * rstd * g1 + be1);
    }
}

extern "C" void kernel_launch(void* const* d_in, const int* in_sizes, int n_in,
                              void* d_out, int out_size, void* d_ws, size_t ws_size,
                              hipStream_t stream) {
    // inputs (setup_inputs dict order): t, h, edge_index, batch_size, W, b, gamma, beta
    const float* h     = (const float*)d_in[1];
    const int*   ei    = (const int*)  d_in[2];   // (2, NE) flat: [0]=src row, [1]=dst row
    const float* Wg    = (const float*)d_in[4];
    const float* b     = (const float*)d_in[5];
    const float* gamma = (const float*)d_in[6];
    const float* beta  = (const float*)d_in[7];
    float* out = (float*)d_out;

    // workspace layout: aggh[NN*D] floats | degi[NN] ints | dinv[NN] floats
    float* aggh = (float*)d_ws;
    int*   degi = (int*)(aggh + (size_t)NN * D);
    float* dinv = (float*)(degi + NN);

    // zero aggh + degi (ws is poisoned 0xAA before every call)
    hipMemsetAsync(d_ws, 0, ((size_t)NN * D + NN) * sizeof(float), stream);
    // zero the tail outputs: zeros_like(edge_index) + zeros_like(batch_size)
    size_t dh_bytes  = (size_t)NN * D * sizeof(float);
    size_t out_bytes = (size_t)out_size * sizeof(float);
    if (out_bytes > dh_bytes)
        hipMemsetAsync((char*)d_out + dh_bytes, 0, out_bytes - dh_bytes, stream);

    k_deg    <<<NE / 256,        256, 0, stream>>>(ei, degi);
    k_dinv   <<<(NN + 255) / 256,256, 0, stream>>>(degi, dinv);
    k_scatter<<<NE * 32 / 256,   256, 0, stream>>>(ei, h, dinv, aggh);
    k_gemm_ln_tanh<<<NN / 16,    256, 0, stream>>>(aggh, h, dinv, Wg, b, gamma, beta, out);
}

// Round 2
// 306.212 us; speedup vs baseline: 4.9997x; 4.9997x over previous
//
#include <hip/hip_runtime.h>
#include <math.h>

#define NN 50000
#define NE 800000
#define D  128
#define SCAN_CHUNK 1024
#define NSCAN ((NN + SCAN_CHUNK - 1) / SCAN_CHUNK)   // 49

// ---------------- in-degree histogram (dst) ----------------
__global__ __launch_bounds__(256) void k_deg(const int* __restrict__ ei,
                                             int* __restrict__ deg) {
    int e = blockIdx.x * 256 + threadIdx.x;   // grid = NE/256 exactly
    atomicAdd(&deg[ei[NE + e]], 1);
}

// ---------------- scan stage A: per-chunk sums + dinv ----------------
__global__ __launch_bounds__(256) void k_scan_a(const int* __restrict__ deg,
                                                int* __restrict__ partial,
                                                float* __restrict__ dinv) {
    __shared__ int red[256];
    int t = threadIdx.x;
    int base = blockIdx.x * SCAN_CHUNK + t * 4;
    int s = 0;
#pragma unroll
    for (int j = 0; j < 4; j++) {
        int i = base + j;
        if (i < NN) {
            int d = deg[i];
            s += d;
            dinv[i] = rsqrtf((float)d + 1.0f);   // +1 self loop
        }
    }
    red[t] = s; __syncthreads();
#pragma unroll
    for (int off = 128; off > 0; off >>= 1) {
        if (t < off) red[t] += red[t + off];
        __syncthreads();
    }
    if (t == 0) partial[blockIdx.x] = red[0];
}

// ---------------- scan stage B: serial scan of 49 partials ----------------
__global__ void k_scan_b(int* __restrict__ partial) {
    if (threadIdx.x == 0) {
        int acc = 0;
        for (int b = 0; b < NSCAN; b++) { int v = partial[b]; partial[b] = acc; acc += v; }
    }
}

// ---------------- scan stage C: per-chunk exclusive scan -> rowoff, cur ------
__global__ __launch_bounds__(256) void k_scan_c(const int* __restrict__ deg,
                                                const int* __restrict__ partial,
                                                int* __restrict__ rowoff,
                                                int* __restrict__ cur) {
    __shared__ int sbuf[256];
    int t = threadIdx.x;
    int base = blockIdx.x * SCAN_CHUNK + t * 4;
    int d[4]; int s = 0;
#pragma unroll
    for (int j = 0; j < 4; j++) {
        d[j] = (base + j < NN) ? deg[base + j] : 0;
        s += d[j];
    }
    sbuf[t] = s; __syncthreads();
    for (int off = 1; off < 256; off <<= 1) {
        int v = (t >= off) ? sbuf[t - off] : 0;
        __syncthreads();
        sbuf[t] += v;
        __syncthreads();
    }
    int ex = sbuf[t] - s + partial[blockIdx.x];
#pragma unroll
    for (int j = 0; j < 4; j++) {
        if (base + j < NN) { rowoff[base + j] = ex; cur[base + j] = ex; }
        ex += d[j];
    }
}

// ---------------- CSR fill (counting-sort placement) ----------------
__global__ __launch_bounds__(256) void k_fill(const int* __restrict__ ei,
                                              int* __restrict__ cur,
                                              int* __restrict__ csr) {
    int e = blockIdx.x * 256 + threadIdx.x;   // grid = NE/256
    int src = ei[e];
    int dst = ei[NE + e];
    int pos = atomicAdd(&cur[dst], 1);
    csr[pos] = src;
}

// ---------------- gather: aggh[n] = dn*(sum dinv[s] h[s] + dn h[n]) ----------
// One wave per node; lane covers dims (lane, lane+64).
__global__ __launch_bounds__(256) void k_gather(const int* __restrict__ rowoff,
                                                const int* __restrict__ deg,
                                                const int* __restrict__ csr,
                                                const float* __restrict__ dinv,
                                                const float* __restrict__ h,
                                                float* __restrict__ aggh) {
    int gt = blockIdx.x * 256 + threadIdx.x;  // grid = NN/4 blocks -> NN waves
    int node = gt >> 6;
    int lane = gt & 63;
    const float* hp = h + (size_t)node * D;
    float dn = dinv[node];
    float x0 = dn * hp[lane];
    float x1 = dn * hp[lane + 64];
    int start = rowoff[node], n = deg[node];
    int j = 0;
    for (; j + 1 < n; j += 2) {
        int s0 = csr[start + j], s1 = csr[start + j + 1];
        float w0 = dinv[s0], w1 = dinv[s1];
        const float* p0 = h + (size_t)s0 * D;
        const float* p1 = h + (size_t)s1 * D;
        x0 += w0 * p0[lane];      x1 += w0 * p0[lane + 64];
        x0 += w1 * p1[lane];      x1 += w1 * p1[lane + 64];
    }
    if (j < n) {
        int s0 = csr[start + j];
        float w0 = dinv[s0];
        const float* p0 = h + (size_t)s0 * D;
        x0 += w0 * p0[lane];      x1 += w0 * p0[lane + 64];
    }
    aggh[(size_t)node * D + lane]      = dn * x0;
    aggh[(size_t)node * D + lane + 64] = dn * x1;
}

// ---------------- fused GEMM + bias + LN + tanh ----------------
// Block 256 = 4 waves; 32 rows/block, 8 rows/wave; lane owns cols (lane, lane+64).
__global__ __launch_bounds__(256) void k_gemm_ln_tanh(
        const float* __restrict__ aggh, const float* __restrict__ Wg,
        const float* __restrict__ b,    const float* __restrict__ gamma,
        const float* __restrict__ beta, float* __restrict__ out) {
    __shared__ float Wl[D * D];    // 64 KB
    __shared__ float xs[32][D];    // 16 KB
    int tid = threadIdx.x;

#pragma unroll
    for (int i = 0; i < 16; i++)
        ((float4*)Wl)[i * 256 + tid] = ((const float4*)Wg)[i * 256 + tid];

    int rowBase = blockIdx.x * 32;
    // stage 32 rows (1024 float4) cooperatively
#pragma unroll
    for (int i = 0; i < 4; i++) {
        int j = i * 256 + tid;          // 0..1023
        int r = j >> 5;
        int c = (j & 31) << 2;
        int row = rowBase + r;
        float4 v = make_float4(0.f, 0.f, 0.f, 0.f);
        if (row < NN) v = *(const float4*)(aggh + (size_t)row * D + c);
        *(float4*)&xs[r][c] = v;
    }
    __syncthreads();

    int w = tid >> 6, lane = tid & 63;
    int r0 = w * 8;
    float b0  = b[lane],     b1  = b[lane + 64];
    float g0  = gamma[lane], g1  = gamma[lane + 64];
    float be0 = beta[lane],  be1 = beta[lane + 64];

    float acc0[8] = {0,0,0,0,0,0,0,0};
    float acc1[8] = {0,0,0,0,0,0,0,0};
    for (int k4 = 0; k4 < D; k4 += 4) {
        float4 xv[8];
#pragma unroll
        for (int r = 0; r < 8; r++) xv[r] = *(const float4*)&xs[r0 + r][k4];
#pragma unroll
        for (int kk = 0; kk < 4; kk++) {
            float w0 = Wl[(k4 + kk) * D + lane];
            float w1 = Wl[(k4 + kk) * D + lane + 64];
#pragma unroll
            for (int r = 0; r < 8; r++) {
                float xk = ((const float*)&xv[r])[kk];
                acc0[r] = fmaf(xk, w0, acc0[r]);
                acc1[r] = fmaf(xk, w1, acc1[r]);
            }
        }
    }

#pragma unroll
    for (int r = 0; r < 8; r++) {
        int row = rowBase + r0 + r;
        float y0 = acc0[r] + b0;
        float y1 = acc1[r] + b1;
        float s = y0 + y1;
#pragma unroll
        for (int off = 32; off > 0; off >>= 1) s += __shfl_xor(s, off, 64);
        float m = s * (1.0f / 128.0f);
        float v0 = y0 - m, v1 = y1 - m;
        float vs = v0 * v0 + v1 * v1;
#pragma unroll
        for (int off = 32; off > 0; off >>= 1) vs += __shfl_xor(vs, off, 64);
        float rstd = rsqrtf(vs * (1.0f / 128.0f) + 1e-5f);
        if (row < NN) {
            out[(size_t)row * D + lane]      = tanhf(v0 * rstd * g0 + be0);
            out[(size_t)row * D + lane + 64] = tanhf(v1 * rstd * g1 + be1);
        }
    }
}

extern "C" void kernel_launch(void* const* d_in, const int* in_sizes, int n_in,
                              void* d_out, int out_size, void* d_ws, size_t ws_size,
                              hipStream_t stream) {
    // inputs: t, h, edge_index, batch_size, W, b, gamma, beta
    const float* h     = (const float*)d_in[1];
    const int*   ei    = (const int*)  d_in[2];
    const float* Wg    = (const float*)d_in[4];
    const float* b     = (const float*)d_in[5];
    const float* gamma = (const float*)d_in[6];
    const float* beta  = (const float*)d_in[7];
    float* out = (float*)d_out;

    // workspace layout
    float* aggh   = (float*)d_ws;                       // NN*D floats
    int*   deg    = (int*)(aggh + (size_t)NN * D);      // NN
    int*   cur    = deg + NN;                           // NN
    int*   rowoff = cur + NN;                           // NN
    float* dinv   = (float*)(rowoff + NN);              // NN
    int*   partial= (int*)(dinv + NN);                  // 64
    int*   csr    = partial + 64;                       // NE

    // zero deg only (ws is poisoned 0xAA before every call)
    hipMemsetAsync(deg, 0, NN * sizeof(int), stream);
    // zero tail outputs (zeros_like(edge_index) + zeros_like(batch_size))
    size_t dh_bytes  = (size_t)NN * D * sizeof(float);
    size_t out_bytes = (size_t)out_size * sizeof(float);
    if (out_bytes > dh_bytes)
        hipMemsetAsync((char*)d_out + dh_bytes, 0, out_bytes - dh_bytes, stream);

    k_deg   <<<NE / 256, 256, 0, stream>>>(ei, deg);
    k_scan_a<<<NSCAN,    256, 0, stream>>>(deg, partial, dinv);
    k_scan_b<<<1,         64, 0, stream>>>(partial);
    k_scan_c<<<NSCAN,    256, 0, stream>>>(deg, partial, rowoff, cur);
    k_fill  <<<NE / 256, 256, 0, stream>>>(ei, cur, csr);
    k_gather<<<NN / 4,   256, 0, stream>>>(rowoff, deg, csr, dinv, h, aggh);
    k_gemm_ln_tanh<<<(NN + 31) / 32, 256, 0, stream>>>(aggh, Wg, b, gamma, beta, out);
}